// Round 4
// baseline (171.080 us; speedup 1.0000x reference)
//
#include <hip/hip_runtime.h>
#include <math.h>

// CantorAttention: B=2, S=2048, DIM=512, H=8, HD=64, K=64
#define B_    2
#define S_    2048
#define DIM_  512
#define H_    8
#define HD_   64
#define K_    64
#define M_    (B_ * S_)          // 4096
#define NQKV_ (3 * DIM_)         // 1536

typedef __attribute__((ext_vector_type(8))) short          short8;    // mfma A/B frag (8 bf16)
typedef __attribute__((ext_vector_type(8))) unsigned short ushort8v;  // 16B move
typedef __attribute__((ext_vector_type(4))) unsigned short ushort4v;  // 8B move
typedef __attribute__((ext_vector_type(4))) float          float4v;   // mfma C/D frag

// ---- bf16 split helpers (RN-even) ------------------------------------------
__device__ __forceinline__ unsigned short f2bf_rn(float f) {
    unsigned int u = __float_as_uint(f);
    return (unsigned short)((u + 0x7FFFu + ((u >> 16) & 1u)) >> 16);
}
__device__ __forceinline__ float bf2f(unsigned short h) {
    return __uint_as_float((unsigned int)h << 16);
}

// async 16B global -> LDS (lane l lands at ldsbase + l*16)
__device__ __forceinline__ void load_lds16(const unsigned short* g, unsigned short* l) {
    __builtin_amdgcn_global_load_lds(
        (const __attribute__((address_space(1))) void*)g,
        (__attribute__((address_space(3))) void*)l, 16, 0, 0);
}

// ---------------------------------------------------------------------------
// prep_x: elementwise split fp32 -> (hi, lo) bf16 arrays. 8 elems/thread.
// ---------------------------------------------------------------------------
__global__ __launch_bounds__(256) void prep_x(const float* __restrict__ X,
                                              unsigned short* __restrict__ Hi,
                                              unsigned short* __restrict__ Lo)
{
    size_t i = ((size_t)blockIdx.x * 256 + threadIdx.x) * 8;
    float4 a = *(const float4*)&X[i];
    float4 b = *(const float4*)&X[i + 4];
    float f[8] = {a.x, a.y, a.z, a.w, b.x, b.y, b.z, b.w};
    ushort8v h, l;
    #pragma unroll
    for (int j = 0; j < 8; ++j) {
        unsigned short hh = f2bf_rn(f[j]);
        h[j] = hh;
        l[j] = f2bf_rn(f[j] - bf2f(hh));
    }
    *(ushort8v*)&Hi[i] = h;
    *(ushort8v*)&Lo[i] = l;
}

// ---------------------------------------------------------------------------
// prep_w: transpose + split W[Kd][N] fp32 -> Whi/Wlo [N][Kd] bf16.
// ---------------------------------------------------------------------------
__global__ __launch_bounds__(256) void prep_w(const float* __restrict__ W,
                                              unsigned short* __restrict__ Whi,
                                              unsigned short* __restrict__ Wlo,
                                              int Kd, int N)
{
    __shared__ float tile[32][33];
    const int k0 = blockIdx.y * 32, n0 = blockIdx.x * 32;
    const int c = threadIdx.x & 31, r8 = threadIdx.x >> 5;
    #pragma unroll
    for (int i = 0; i < 4; ++i) {
        int r = r8 + i * 8;
        tile[r][c] = W[(size_t)(k0 + r) * N + n0 + c];
    }
    __syncthreads();
    #pragma unroll
    for (int i = 0; i < 4; ++i) {
        int r = r8 + i * 8;                 // n offset
        float f = tile[c][r];               // = W[k0+c][n0+r]
        unsigned short hi = f2bf_rn(f);
        unsigned short lo = f2bf_rn(f - bf2f(hi));
        Whi[(size_t)(n0 + r) * Kd + k0 + c] = hi;
        Wlo[(size_t)(n0 + r) * Kd + k0 + c] = lo;
    }
}

// ---------------------------------------------------------------------------
// Split-bf16 MFMA GEMM (3 MFMAs: hi*hi + lo*hi + hi*lo).
// m97-style staging: global_load_lds width=16 direct to unpadded [row][32]
// LDS tiles (no VGPR round-trip, no LDS store instructions). BK=32.
//   mode 0: row-major C.  mode 1: qkv scatter into Q/K/V [B,H,S,HD].
// ---------------------------------------------------------------------------
template<int BM, int BN, int WM, int WN>
__global__ __launch_bounds__(256) void gemm_mfma(
    const unsigned short* __restrict__ Ahi, const unsigned short* __restrict__ Alo,
    const unsigned short* __restrict__ Whi, const unsigned short* __restrict__ Wlo,
    const float* __restrict__ bias, float* __restrict__ C,
    float* __restrict__ Qo, float* __restrict__ Ko, float* __restrict__ Vo,
    int N, int Kd, int mode)
{
    constexpr int TM = WM / 16, TN = WN / 16;
    constexpr int WAVES_N = BN / WN;
    __shared__ unsigned short Ah[BM][32], Al[BM][32];
    __shared__ unsigned short Bh[BN][32], Bl[BN][32];

    const int t = threadIdx.x, lane = t & 63, wave = t >> 6;
    const int wm = (wave / WAVES_N) * WM, wn = (wave % WAVES_N) * WN;
    const int m0 = blockIdx.y * BM, n0 = blockIdx.x * BN;
    const int l15 = lane & 15, l4 = lane >> 4;

    // staging geometry: 1 KB per wave-issue = 16 rows x 64 B; lane l covers
    // row base+ (l>>2), k-chunk (l&3)*8 elems (16 B) -> LDS off = l*16.
    const int srow = lane >> 2;          // 0..15
    const int scol = (lane & 3) * 8;     // 0,8,16,24

    float4v acc[TM][TN];
    #pragma unroll
    for (int i = 0; i < TM; ++i)
        #pragma unroll
        for (int j = 0; j < TN; ++j)
            #pragma unroll
            for (int r = 0; r < 4; ++r) acc[i][j][r] = 0.f;

    for (int k0 = 0; k0 < Kd; k0 += 32) {
        #pragma unroll
        for (int c = wave; c < BM / 16; c += 4) {
            size_t g = (size_t)(m0 + c * 16 + srow) * Kd + k0 + scol;
            load_lds16(&Ahi[g], &Ah[c * 16][0]);
            load_lds16(&Alo[g], &Al[c * 16][0]);
        }
        #pragma unroll
        for (int c = wave; c < BN / 16; c += 4) {
            size_t g = (size_t)(n0 + c * 16 + srow) * Kd + k0 + scol;
            load_lds16(&Whi[g], &Bh[c * 16][0]);
            load_lds16(&Wlo[g], &Bl[c * 16][0]);
        }
        __syncthreads();   // drains vmcnt (global_load_lds) before frag reads

        short8 fa_h[TM], fa_l[TM], fb_h[TN], fb_l[TN];
        #pragma unroll
        for (int im = 0; im < TM; ++im) {
            fa_h[im] = *(const short8*)&Ah[wm + im * 16 + l15][l4 * 8];
            fa_l[im] = *(const short8*)&Al[wm + im * 16 + l15][l4 * 8];
        }
        #pragma unroll
        for (int in = 0; in < TN; ++in) {
            fb_h[in] = *(const short8*)&Bh[wn + in * 16 + l15][l4 * 8];
            fb_l[in] = *(const short8*)&Bl[wn + in * 16 + l15][l4 * 8];
        }
        #pragma unroll
        for (int im = 0; im < TM; ++im)
            #pragma unroll
            for (int in = 0; in < TN; ++in) {
                acc[im][in] = __builtin_amdgcn_mfma_f32_16x16x32_bf16(fa_h[im], fb_h[in], acc[im][in], 0, 0, 0);
                acc[im][in] = __builtin_amdgcn_mfma_f32_16x16x32_bf16(fa_l[im], fb_h[in], acc[im][in], 0, 0, 0);
                acc[im][in] = __builtin_amdgcn_mfma_f32_16x16x32_bf16(fa_h[im], fb_l[in], acc[im][in], 0, 0, 0);
            }
        __syncthreads();
    }

    // epilogue: D row = (lane>>4)*4 + reg, col = lane&15  [m89-verified layout]
    if (mode == 0) {
        #pragma unroll
        for (int in = 0; in < TN; ++in) {
            int n = n0 + wn + in * 16 + l15;
            float bv = bias[n];
            #pragma unroll
            for (int im = 0; im < TM; ++im) {
                int mb = m0 + wm + im * 16 + l4 * 4;
                #pragma unroll
                for (int r = 0; r < 4; ++r)
                    C[(size_t)(mb + r) * N + n] = acc[im][in][r] + bv;
            }
        }
    } else {
        #pragma unroll
        for (int in = 0; in < TN; ++in) {
            int n = n0 + wn + in * 16 + l15;
            int which = n >> 9, h = (n >> 6) & 7, d = n & 63;
            float* dst = (which == 0) ? Qo : (which == 1 ? Ko : Vo);
            float bv = bias[n];
            #pragma unroll
            for (int im = 0; im < TM; ++im) {
                int mb = m0 + wm + im * 16 + l4 * 4;
                #pragma unroll
                for (int r = 0; r < 4; ++r) {
                    int m = mb + r, b = m >> 11, s = m & 2047;
                    dst[(((size_t)b * H_ + h) * S_ + s) * HD_ + d] = acc[im][in][r] + bv;
                }
            }
        }
    }
}

// ---------------------------------------------------------------------------
// Gathered attention, one wave per query, XCD-pinned by (b,h).
// Phase 1: 4 lanes/key, 64B contiguous per lane, quad shuffle-reduce.
// Phase 2: 4 keys/iter, float4 V loads, weights/routes via __shfl (no LDS in
// the hot loop), cross-group shfl_xor reduce at the end.
// ---------------------------------------------------------------------------
__global__ __launch_bounds__(256) void attn_kernel(
    const float* __restrict__ Q, const float* __restrict__ Kp,
    const float* __restrict__ V, const int* __restrict__ routes,
    unsigned short* __restrict__ Ohi, unsigned short* __restrict__ Olo)
{
    __shared__ float q_s[4][64];
    __shared__ float w_s[4][64];

    const int wv = threadIdx.x >> 6, lane = threadIdx.x & 63;

    // XCD-aware swizzle: 8192 blocks; xcd = blk&7; 2 bh per xcd; s ordered.
    const int blk  = blockIdx.x;
    const int xcd  = blk & 7;
    const int idx  = blk >> 3;            // [0, 1024)
    const int half = idx >> 9;            // 0 or 1
    const int sblk = idx & 511;           // [0, 512)
    const int bh   = xcd | (half << 3);   // [0, 16)
    const int s    = sblk * 4 + wv;
    const int b    = bh >> 3, h = bh & 7;

    q_s[wv][lane] = Q[((size_t)bh * S_ + s) * HD_ + lane];
    const int r_own = routes[s * K_ + lane];
    __syncthreads();

    // phase 1: scores. 4 lanes per key; key j = pass*16 + (lane>>2).
    const int p = lane & 3, jl = lane >> 2;
    float qv[16];
    #pragma unroll
    for (int i = 0; i < 16; ++i) qv[i] = q_s[wv][p * 16 + i];

    const float* kbase = Kp + (size_t)bh * S_ * HD_;
    #pragma unroll
    for (int pass = 0; pass < 4; ++pass) {
        int j = pass * 16 + jl;
        int rj = __shfl(r_own, j);
        const float* kp = kbase + (size_t)rj * HD_ + p * 16;
        float partial = 0.f;
        #pragma unroll
        for (int i = 0; i < 16; i += 4) {
            float4 kv = *(const float4*)(kp + i);
            partial += qv[i] * kv.x + qv[i + 1] * kv.y + qv[i + 2] * kv.z + qv[i + 3] * kv.w;
        }
        partial += __shfl_xor(partial, 1);
        partial += __shfl_xor(partial, 2);
        if (p == 0) w_s[wv][j] = partial * 0.125f;
    }
    __syncthreads();

    // softmax over 64 keys, all in registers/shuffles
    float sc = w_s[wv][lane];
    float mx = sc;
    #pragma unroll
    for (int off = 32; off >= 1; off >>= 1) mx = fmaxf(mx, __shfl_xor(mx, off));
    float e = __expf(sc - mx);
    float sum = e;
    #pragma unroll
    for (int off = 32; off >= 1; off >>= 1) sum += __shfl_xor(sum, off);
    const float w = e / sum;              // weight for key = lane

    // phase 2: 4 keys per iteration; lane handles key (4i + g), d-slice dsl.
    const int g = lane >> 4, dsl = (lane & 15) * 4;
    const float* vbase = V + (size_t)bh * S_ * HD_;
    float ax = 0.f, ay = 0.f, az = 0.f, aw = 0.f;
    #pragma unroll
    for (int i = 0; i < 16; ++i) {
        int key = i * 4 + g;
        float wj = __shfl(w, key);
        int   rj = __shfl(r_own, key);
        float4 vv = *(const float4*)&vbase[(size_t)rj * HD_ + dsl];
        ax += wj * vv.x; ay += wj * vv.y; az += wj * vv.z; aw += wj * vv.w;
    }
    // reduce over the 4 key-groups (lanes l, l^16, l^32, l^48 share dsl)
    #pragma unroll
    for (int off = 16; off <= 32; off <<= 1) {
        ax += __shfl_xor(ax, off);
        ay += __shfl_xor(ay, off);
        az += __shfl_xor(az, off);
        aw += __shfl_xor(aw, off);
    }

    if (g == 0) {
        float o[4] = {ax, ay, az, aw};
        ushort4v hv, lv;
        #pragma unroll
        for (int i = 0; i < 4; ++i) {
            unsigned short hh = f2bf_rn(o[i]);
            hv[i] = hh;
            lv[i] = f2bf_rn(o[i] - bf2f(hh));
        }
        size_t oi = ((size_t)b * S_ + s) * DIM_ + h * HD_ + dsl;
        *(ushort4v*)&Ohi[oi] = hv;
        *(ushort4v*)&Olo[oi] = lv;
    }
}

// ---------------------------------------------------------------------------
// ws layout (bytes):
//   0    Q 8MB | 8M K 8MB | 16M V 8MB | 24M x_hi/attn_hi 4MB | 28M x_lo/attn_lo 4MB
//   32M  Wqkv_hi 1.5M | +1.5M Wqkv_lo | +3M Wout_hi 0.5M | +3.5M Wout_lo
// ---------------------------------------------------------------------------
extern "C" void kernel_launch(void* const* d_in, const int* in_sizes, int n_in,
                              void* d_out, int out_size, void* d_ws, size_t ws_size,
                              hipStream_t stream)
{
    const float* x      = (const float*)d_in[0];
    const float* Wqkv   = (const float*)d_in[1];
    const float* bqkv   = (const float*)d_in[2];
    const float* Wout   = (const float*)d_in[3];
    const float* bout   = (const float*)d_in[4];
    const int*   routes = (const int*)d_in[5];
    float* out = (float*)d_out;

    char* w = (char*)d_ws;
    float* Q  = (float*)(w);
    float* Kp = (float*)(w + (8u << 20));
    float* V  = (float*)(w + (16u << 20));
    unsigned short* xh  = (unsigned short*)(w + (24u << 20));
    unsigned short* xl  = (unsigned short*)(w + (28u << 20));
    unsigned short* ah  = xh;   // aliased: free after qkv gemm
    unsigned short* al  = xl;
    unsigned short* wqh = (unsigned short*)(w + (32u << 20));
    unsigned short* wql = (unsigned short*)(w + (32u << 20) + 1572864u);
    unsigned short* woh = (unsigned short*)(w + (32u << 20) + 3145728u);
    unsigned short* wol = (unsigned short*)(w + (32u << 20) + 3670016u);

    dim3 blk(256);

    prep_x<<<dim3((M_ * DIM_) / (256 * 8)), blk, 0, stream>>>(x, xh, xl);
    prep_w<<<dim3(NQKV_ / 32, DIM_ / 32), blk, 0, stream>>>(Wqkv, wqh, wql, DIM_, NQKV_);
    prep_w<<<dim3(DIM_ / 32, DIM_ / 32), blk, 0, stream>>>(Wout, woh, wol, DIM_, DIM_);

    // qkv: M=4096, N=1536, K=512 -> 12x32 = 384 blocks
    gemm_mfma<128, 128, 64, 64><<<dim3(NQKV_ / 128, M_ / 128), blk, 0, stream>>>(
        xh, xl, wqh, wql, bqkv, nullptr, Q, Kp, V, NQKV_, DIM_, 1);

    attn_kernel<<<dim3((B_ * H_ * S_) / 4), blk, 0, stream>>>(Q, Kp, V, routes, ah, al);

    // out-proj: M=4096, N=512, K=512 -> 4x64 = 256 blocks
    gemm_mfma<64, 128, 32, 64><<<dim3(DIM_ / 128, M_ / 64), blk, 0, stream>>>(
        ah, al, woh, wol, bout, out, nullptr, nullptr, nullptr, DIM_, DIM_, 0);
}

// Round 5
// 166.443 us; speedup vs baseline: 1.0279x; 1.0279x over previous
//
#include <hip/hip_runtime.h>
#include <math.h>

// CantorAttention: B=2, S=2048, DIM=512, H=8, HD=64, K=64
#define B_    2
#define S_    2048
#define DIM_  512
#define H_    8
#define HD_   64
#define K_    64
#define M_    (B_ * S_)          // 4096
#define NQKV_ (3 * DIM_)         // 1536

typedef __attribute__((ext_vector_type(8))) short          short8;    // mfma A/B frag (8 bf16)
typedef __attribute__((ext_vector_type(8))) unsigned short ushort8v;  // 16B move
typedef __attribute__((ext_vector_type(4))) unsigned short ushort4v;  // 8B move
typedef __attribute__((ext_vector_type(4))) float          float4v;   // mfma C/D frag

// ---- bf16 split helpers (RN-even) ------------------------------------------
__device__ __forceinline__ unsigned short f2bf_rn(float f) {
    unsigned int u = __float_as_uint(f);
    return (unsigned short)((u + 0x7FFFu + ((u >> 16) & 1u)) >> 16);
}
__device__ __forceinline__ float bf2f(unsigned short h) {
    return __uint_as_float((unsigned int)h << 16);
}

// async 16B global -> LDS (lane l lands at ldsbase + l*16)
__device__ __forceinline__ void load_lds16(const unsigned short* g, unsigned short* l) {
    __builtin_amdgcn_global_load_lds(
        (const __attribute__((address_space(1))) void*)g,
        (__attribute__((address_space(3))) void*)l, 16, 0, 0);
}

// ---------------------------------------------------------------------------
// prep_x: elementwise split fp32 -> (hi, lo) bf16 arrays. 8 elems/thread.
// ---------------------------------------------------------------------------
__global__ __launch_bounds__(256) void prep_x(const float* __restrict__ X,
                                              unsigned short* __restrict__ Hi,
                                              unsigned short* __restrict__ Lo)
{
    size_t i = ((size_t)blockIdx.x * 256 + threadIdx.x) * 8;
    float4 a = *(const float4*)&X[i];
    float4 b = *(const float4*)&X[i + 4];
    float f[8] = {a.x, a.y, a.z, a.w, b.x, b.y, b.z, b.w};
    ushort8v h, l;
    #pragma unroll
    for (int j = 0; j < 8; ++j) {
        unsigned short hh = f2bf_rn(f[j]);
        h[j] = hh;
        l[j] = f2bf_rn(f[j] - bf2f(hh));
    }
    *(ushort8v*)&Hi[i] = h;
    *(ushort8v*)&Lo[i] = l;
}

// ---------------------------------------------------------------------------
// prep_w: transpose + split W[Kd][N] fp32 -> Whi/Wlo [N][Kd] bf16.
// ---------------------------------------------------------------------------
__global__ __launch_bounds__(256) void prep_w(const float* __restrict__ W,
                                              unsigned short* __restrict__ Whi,
                                              unsigned short* __restrict__ Wlo,
                                              int Kd, int N)
{
    __shared__ float tile[32][33];
    const int k0 = blockIdx.y * 32, n0 = blockIdx.x * 32;
    const int c = threadIdx.x & 31, r8 = threadIdx.x >> 5;
    #pragma unroll
    for (int i = 0; i < 4; ++i) {
        int r = r8 + i * 8;
        tile[r][c] = W[(size_t)(k0 + r) * N + n0 + c];
    }
    __syncthreads();
    #pragma unroll
    for (int i = 0; i < 4; ++i) {
        int r = r8 + i * 8;                 // n offset
        float f = tile[c][r];               // = W[k0+c][n0+r]
        unsigned short hi = f2bf_rn(f);
        unsigned short lo = f2bf_rn(f - bf2f(hi));
        Whi[(size_t)(n0 + r) * Kd + k0 + c] = hi;
        Wlo[(size_t)(n0 + r) * Kd + k0 + c] = lo;
    }
}

// ---------------------------------------------------------------------------
// Split-bf16 MFMA GEMM (3 MFMAs: hi*hi + lo*hi + hi*lo).
// global_load_lds width=16 staging into unpadded [row][32] LDS. BK=32.
// Tiles sized so grid >= 2 blocks/CU (512 blocks for both uses).
//   mode 0: row-major C.  mode 1: qkv scatter into Q/K/V [B,H,S,HD].
// ---------------------------------------------------------------------------
template<int BM, int BN, int WM, int WN>
__global__ __launch_bounds__(256) void gemm_mfma(
    const unsigned short* __restrict__ Ahi, const unsigned short* __restrict__ Alo,
    const unsigned short* __restrict__ Whi, const unsigned short* __restrict__ Wlo,
    const float* __restrict__ bias, float* __restrict__ C,
    float* __restrict__ Qo, float* __restrict__ Ko, float* __restrict__ Vo,
    int N, int Kd, int mode)
{
    constexpr int TM = WM / 16, TN = WN / 16;
    constexpr int WAVES_N = BN / WN;
    __shared__ unsigned short Ah[BM][32], Al[BM][32];
    __shared__ unsigned short Bh[BN][32], Bl[BN][32];

    const int t = threadIdx.x, lane = t & 63, wave = t >> 6;
    const int wm = (wave / WAVES_N) * WM, wn = (wave % WAVES_N) * WN;
    const int m0 = blockIdx.y * BM, n0 = blockIdx.x * BN;
    const int l15 = lane & 15, l4 = lane >> 4;

    // staging: 1 KB per wave-issue = 16 rows x 64 B; lane l covers row
    // base+(l>>2), k-chunk (l&3)*8 elems -> LDS off = l*16.
    const int srow = lane >> 2;          // 0..15
    const int scol = (lane & 3) * 8;     // 0,8,16,24

    float4v acc[TM][TN];
    #pragma unroll
    for (int i = 0; i < TM; ++i)
        #pragma unroll
        for (int j = 0; j < TN; ++j)
            #pragma unroll
            for (int r = 0; r < 4; ++r) acc[i][j][r] = 0.f;

    for (int k0 = 0; k0 < Kd; k0 += 32) {
        #pragma unroll
        for (int c = wave; c < BM / 16; c += 4) {
            size_t g = (size_t)(m0 + c * 16 + srow) * Kd + k0 + scol;
            load_lds16(&Ahi[g], &Ah[c * 16][0]);
            load_lds16(&Alo[g], &Al[c * 16][0]);
        }
        #pragma unroll
        for (int c = wave; c < BN / 16; c += 4) {
            size_t g = (size_t)(n0 + c * 16 + srow) * Kd + k0 + scol;
            load_lds16(&Whi[g], &Bh[c * 16][0]);
            load_lds16(&Wlo[g], &Bl[c * 16][0]);
        }
        __syncthreads();   // drains vmcnt before frag reads

        short8 fa_h[TM], fa_l[TM], fb_h[TN], fb_l[TN];
        #pragma unroll
        for (int im = 0; im < TM; ++im) {
            fa_h[im] = *(const short8*)&Ah[wm + im * 16 + l15][l4 * 8];
            fa_l[im] = *(const short8*)&Al[wm + im * 16 + l15][l4 * 8];
        }
        #pragma unroll
        for (int in = 0; in < TN; ++in) {
            fb_h[in] = *(const short8*)&Bh[wn + in * 16 + l15][l4 * 8];
            fb_l[in] = *(const short8*)&Bl[wn + in * 16 + l15][l4 * 8];
        }
        #pragma unroll
        for (int im = 0; im < TM; ++im)
            #pragma unroll
            for (int in = 0; in < TN; ++in) {
                acc[im][in] = __builtin_amdgcn_mfma_f32_16x16x32_bf16(fa_h[im], fb_h[in], acc[im][in], 0, 0, 0);
                acc[im][in] = __builtin_amdgcn_mfma_f32_16x16x32_bf16(fa_l[im], fb_h[in], acc[im][in], 0, 0, 0);
                acc[im][in] = __builtin_amdgcn_mfma_f32_16x16x32_bf16(fa_h[im], fb_l[in], acc[im][in], 0, 0, 0);
            }
        __syncthreads();
    }

    // epilogue: D row = (lane>>4)*4 + reg, col = lane&15  [m89-verified layout]
    if (mode == 0) {
        #pragma unroll
        for (int in = 0; in < TN; ++in) {
            int n = n0 + wn + in * 16 + l15;
            float bv = bias[n];
            #pragma unroll
            for (int im = 0; im < TM; ++im) {
                int mb = m0 + wm + im * 16 + l4 * 4;
                #pragma unroll
                for (int r = 0; r < 4; ++r)
                    C[(size_t)(mb + r) * N + n] = acc[im][in][r] + bv;
            }
        }
    } else {
        #pragma unroll
        for (int in = 0; in < TN; ++in) {
            int n = n0 + wn + in * 16 + l15;
            int which = n >> 9, h = (n >> 6) & 7, d = n & 63;
            float* dst = (which == 0) ? Qo : (which == 1 ? Ko : Vo);
            float bv = bias[n];
            #pragma unroll
            for (int im = 0; im < TM; ++im) {
                int mb = m0 + wm + im * 16 + l4 * 4;
                #pragma unroll
                for (int r = 0; r < 4; ++r) {
                    int m = mb + r, b = m >> 11, s = m & 2047;
                    dst[(((size_t)b * H_ + h) * S_ + s) * HD_ + d] = acc[im][in][r] + bv;
                }
            }
        }
    }
}

// ---------------------------------------------------------------------------
// Gathered attention, TWO queries per wave (interleaved independent chains
// for latency hiding), XCD-pinned by (b,h). 4096 blocks.
// ---------------------------------------------------------------------------
__global__ __launch_bounds__(256) void attn_kernel(
    const float* __restrict__ Q, const float* __restrict__ Kp,
    const float* __restrict__ V, const int* __restrict__ routes,
    unsigned short* __restrict__ Ohi, unsigned short* __restrict__ Olo)
{
    __shared__ float q_s[4][2][64];
    __shared__ float w_s[4][2][64];

    const int wv = threadIdx.x >> 6, lane = threadIdx.x & 63;

    // XCD swizzle: 4096 blocks; xcd = blk&7; 2 bh per xcd; s ordered.
    const int blk  = blockIdx.x;
    const int xcd  = blk & 7;
    const int idx  = blk >> 3;            // [0, 512)
    const int half = idx >> 8;            // 0 or 1
    const int sblk = idx & 255;           // [0, 256)
    const int bh   = xcd | (half << 3);   // [0, 16)
    const int s0   = sblk * 8 + wv * 2;   // this wave: s0, s0+1
    const int b    = bh >> 3, h = bh & 7;

    q_s[wv][0][lane] = Q[((size_t)bh * S_ + s0) * HD_ + lane];
    q_s[wv][1][lane] = Q[((size_t)bh * S_ + s0 + 1) * HD_ + lane];
    const int r0 = routes[s0 * K_ + lane];
    const int r1 = routes[(s0 + 1) * K_ + lane];
    __syncthreads();

    // phase 1: scores, 4 lanes/key, both queries interleaved.
    const int p = lane & 3, jl = lane >> 2;
    float qv0[16], qv1[16];
    #pragma unroll
    for (int i = 0; i < 16; ++i) {
        qv0[i] = q_s[wv][0][p * 16 + i];
        qv1[i] = q_s[wv][1][p * 16 + i];
    }

    const float* kbase = Kp + (size_t)bh * S_ * HD_;
    #pragma unroll
    for (int pass = 0; pass < 4; ++pass) {
        int j = pass * 16 + jl;
        int rj0 = __shfl(r0, j);
        int rj1 = __shfl(r1, j);
        const float* kp0 = kbase + (size_t)rj0 * HD_ + p * 16;
        const float* kp1 = kbase + (size_t)rj1 * HD_ + p * 16;
        float pa = 0.f, pb = 0.f;
        #pragma unroll
        for (int i = 0; i < 16; i += 4) {
            float4 k0v = *(const float4*)(kp0 + i);
            float4 k1v = *(const float4*)(kp1 + i);
            pa += qv0[i] * k0v.x + qv0[i + 1] * k0v.y + qv0[i + 2] * k0v.z + qv0[i + 3] * k0v.w;
            pb += qv1[i] * k1v.x + qv1[i + 1] * k1v.y + qv1[i + 2] * k1v.z + qv1[i + 3] * k1v.w;
        }
        pa += __shfl_xor(pa, 1);  pb += __shfl_xor(pb, 1);
        pa += __shfl_xor(pa, 2);  pb += __shfl_xor(pb, 2);
        if (p == 0) { w_s[wv][0][j] = pa * 0.125f; w_s[wv][1][j] = pb * 0.125f; }
    }
    __syncthreads();

    // softmax (two independent shuffle chains)
    float sa = w_s[wv][0][lane], sb = w_s[wv][1][lane];
    float ma = sa, mb = sb;
    #pragma unroll
    for (int off = 32; off >= 1; off >>= 1) {
        ma = fmaxf(ma, __shfl_xor(ma, off));
        mb = fmaxf(mb, __shfl_xor(mb, off));
    }
    float ea = __expf(sa - ma), eb = __expf(sb - mb);
    float su_a = ea, su_b = eb;
    #pragma unroll
    for (int off = 32; off >= 1; off >>= 1) {
        su_a += __shfl_xor(su_a, off);
        su_b += __shfl_xor(su_b, off);
    }
    const float w0 = ea / su_a, w1 = eb / su_b;   // weight for key = lane

    // phase 2: 4 keys/iter per query; lane: key-group g, d-slice dsl.
    const int g = lane >> 4, dsl = (lane & 15) * 4;
    const float* vbase = V + (size_t)bh * S_ * HD_;
    float a0x = 0.f, a0y = 0.f, a0z = 0.f, a0w = 0.f;
    float a1x = 0.f, a1y = 0.f, a1z = 0.f, a1w = 0.f;
    #pragma unroll
    for (int i = 0; i < 16; ++i) {
        int key = i * 4 + g;
        float wj0 = __shfl(w0, key), wj1 = __shfl(w1, key);
        int   rj0 = __shfl(r0, key), rj1 = __shfl(r1, key);
        float4 v0 = *(const float4*)&vbase[(size_t)rj0 * HD_ + dsl];
        float4 v1 = *(const float4*)&vbase[(size_t)rj1 * HD_ + dsl];
        a0x += wj0 * v0.x; a0y += wj0 * v0.y; a0z += wj0 * v0.z; a0w += wj0 * v0.w;
        a1x += wj1 * v1.x; a1y += wj1 * v1.y; a1z += wj1 * v1.z; a1w += wj1 * v1.w;
    }
    #pragma unroll
    for (int off = 16; off <= 32; off <<= 1) {
        a0x += __shfl_xor(a0x, off); a0y += __shfl_xor(a0y, off);
        a0z += __shfl_xor(a0z, off); a0w += __shfl_xor(a0w, off);
        a1x += __shfl_xor(a1x, off); a1y += __shfl_xor(a1y, off);
        a1z += __shfl_xor(a1z, off); a1w += __shfl_xor(a1w, off);
    }

    if (g == 0) {
        float o0[4] = {a0x, a0y, a0z, a0w};
        float o1[4] = {a1x, a1y, a1z, a1w};
        ushort4v h0, l0, h1, l1;
        #pragma unroll
        for (int i = 0; i < 4; ++i) {
            unsigned short hh0 = f2bf_rn(o0[i]);
            h0[i] = hh0; l0[i] = f2bf_rn(o0[i] - bf2f(hh0));
            unsigned short hh1 = f2bf_rn(o1[i]);
            h1[i] = hh1; l1[i] = f2bf_rn(o1[i] - bf2f(hh1));
        }
        size_t oi0 = ((size_t)b * S_ + s0) * DIM_ + h * HD_ + dsl;
        size_t oi1 = oi0 + DIM_;
        *(ushort4v*)&Ohi[oi0] = h0;  *(ushort4v*)&Olo[oi0] = l0;
        *(ushort4v*)&Ohi[oi1] = h1;  *(ushort4v*)&Olo[oi1] = l1;
    }
}

// ---------------------------------------------------------------------------
// ws layout (bytes):
//   0    Q 8MB | 8M K 8MB | 16M V 8MB | 24M x_hi/attn_hi 4MB | 28M x_lo/attn_lo 4MB
//   32M  Wqkv_hi 1.5M | +1.5M Wqkv_lo | +3M Wout_hi 0.5M | +3.5M Wout_lo
// ---------------------------------------------------------------------------
extern "C" void kernel_launch(void* const* d_in, const int* in_sizes, int n_in,
                              void* d_out, int out_size, void* d_ws, size_t ws_size,
                              hipStream_t stream)
{
    const float* x      = (const float*)d_in[0];
    const float* Wqkv   = (const float*)d_in[1];
    const float* bqkv   = (const float*)d_in[2];
    const float* Wout   = (const float*)d_in[3];
    const float* bout   = (const float*)d_in[4];
    const int*   routes = (const int*)d_in[5];
    float* out = (float*)d_out;

    char* w = (char*)d_ws;
    float* Q  = (float*)(w);
    float* Kp = (float*)(w + (8u << 20));
    float* V  = (float*)(w + (16u << 20));
    unsigned short* xh  = (unsigned short*)(w + (24u << 20));
    unsigned short* xl  = (unsigned short*)(w + (28u << 20));
    unsigned short* ah  = xh;   // aliased: free after qkv gemm
    unsigned short* al  = xl;
    unsigned short* wqh = (unsigned short*)(w + (32u << 20));
    unsigned short* wql = (unsigned short*)(w + (32u << 20) + 1572864u);
    unsigned short* woh = (unsigned short*)(w + (32u << 20) + 3145728u);
    unsigned short* wol = (unsigned short*)(w + (32u << 20) + 3670016u);

    dim3 blk(256);

    prep_x<<<dim3((M_ * DIM_) / (256 * 8)), blk, 0, stream>>>(x, xh, xl);
    prep_w<<<dim3(NQKV_ / 32, DIM_ / 32), blk, 0, stream>>>(Wqkv, wqh, wql, DIM_, NQKV_);
    prep_w<<<dim3(DIM_ / 32, DIM_ / 32), blk, 0, stream>>>(Wout, woh, wol, DIM_, DIM_);

    // qkv: M=4096, N=1536, K=512 -> 16x32 = 512 blocks (2/CU)
    gemm_mfma<128, 96, 64, 48><<<dim3(NQKV_ / 96, M_ / 128), blk, 0, stream>>>(
        xh, xl, wqh, wql, bqkv, nullptr, Q, Kp, V, NQKV_, DIM_, 1);

    attn_kernel<<<dim3((B_ * H_ * S_) / 8), blk, 0, stream>>>(Q, Kp, V, routes, ah, al);

    // out-proj: M=4096, N=512, K=512 -> 8x64 = 512 blocks (2/CU)
    gemm_mfma<64, 64, 32, 32><<<dim3(DIM_ / 64, M_ / 64), blk, 0, stream>>>(
        ah, al, woh, wol, bout, out, nullptr, nullptr, nullptr, DIM_, DIM_, 0);
}